// Round 15
// baseline (365.239 us; speedup 1.0000x reference)
//
#include <hip/hip_runtime.h>
#include <stdint.h>

// DSA sparse attention, MI355X. T=512 tok, H=128 heads, K=512 selected keys,
// C=576 (512 lora + 64 rope), S=8192 cache rows.
// Pipeline: prep (kv->bf16 + rope copy, SCALE folded), q_lat GEMM,
// scores_fused (QK^T + row softmax -> P2 in attn A-frag order), attn GEMM,
// out GEMM. MFMA tiling per m90/m92.
//
// R16->R17: softmax fused into scores (P roundtrip deleted): 384.6->361.9.
// R17->R18/R19: 1024-thr/16-wave occupancy round: 361.9->352.9. scores 84->74,
//         occ 20->38% (2 blk/CU). BUT wave grid 4hq x 4kq made each B-frag be
//         read by 4 waves: 256KB ds_read/CU-iter (~2k cyc) dominates; bank
//         conflict doubled to 4.7M; MfmaUtil only 20.6%.
// R19->R20: combine the two verified wins: R17's fragment-efficient shape
//         (512 thr, 8 waves = 2 head-half x 4 key-quarter, acc[4][8] -> each
//         B-frag read by 2 waves, LDS B-traffic/CU-iter halved to 128KB) +
//         R19's depth-2 staging (scores Bs[2] 64KB+4KB, attn St[2] 64KB ->
//         2 blocks/CU retained, 16 waves/CU). vm-queues: scores uniform
//         vmcnt(4) (prologue [DMA0 x4|fence|af x4]); attn vmcnt(8) ks<15 /
//         vmcnt(4) @15 with 1-tile idx lookahead. Same MFMA count per CU.

#define SCALE 0.041666666666666664f  // (512+64)^-0.5

typedef __bf16 bf16x8 __attribute__((ext_vector_type(8)));
typedef float floatx4 __attribute__((ext_vector_type(4)));
typedef unsigned int uint32x2 __attribute__((ext_vector_type(2)));
typedef unsigned int uint32x4 __attribute__((ext_vector_type(4)));

static __device__ __forceinline__ unsigned short f2bf(float f) {
  unsigned int u = __builtin_bit_cast(unsigned int, f);
  u += 0x7FFF + ((u >> 16) & 1);  // RNE
  return (unsigned short)(u >> 16);
}
static __device__ __forceinline__ float bf2f(unsigned short h) {
  unsigned int u = ((unsigned int)h) << 16;
  return __builtin_bit_cast(float, u);
}
static __device__ __forceinline__ unsigned int pack2(float lo, float hi) {
  return (unsigned int)f2bf(lo) | ((unsigned int)f2bf(hi) << 16);
}
// async global->LDS, 16B per lane; LDS dest = wave base + lane*16 (m97 pattern)
static __device__ __forceinline__ void ldsdma16(const void* g, void* l) {
  __builtin_amdgcn_global_load_lds(
      (const __attribute__((address_space(1))) void*)g,
      (__attribute__((address_space(3))) void*)l, 16, 0, 0);
}
// IR-level memory fence + machine-sched fence: pins vm-op issue order
static __device__ __forceinline__ void issue_fence() {
  asm volatile("" ::: "memory");
  __builtin_amdgcn_sched_barrier(0);
}
// 32-bit LDS byte address for inline-asm DS ops
static __device__ __forceinline__ unsigned int lds_addr(const void* p) {
  return (unsigned int)(unsigned long long)(
      (__attribute__((address_space(3))) const void*)p);
}
// hardware transpose read: lane l gets column (l&15) of the 4x16 bf16 subtile
#define TR64(dst, addr, OFF) \
  asm volatile("ds_read_b64_tr_b16 %0, %1 offset:" OFF : "=v"(dst) : "v"(addr))

// stage 8 fp32 -> 8 bf16 into LDS (16B aligned)
static __device__ __forceinline__ void stage8_f32(const float* __restrict__ src,
                                                  unsigned short* dst) {
  const float4* s4 = reinterpret_cast<const float4*>(src);
  float4 v0 = s4[0], v1 = s4[1];
  uint4 o;
  o.x = pack2(v0.x, v0.y); o.y = pack2(v0.z, v0.w);
  o.z = pack2(v1.x, v1.y); o.w = pack2(v1.z, v1.w);
  *reinterpret_cast<uint4*>(dst) = o;
}

static __device__ __forceinline__ void mfma_4x4(const unsigned short* As,
                                                const unsigned short* Bs,
                                                int wm, int wn, int l15, int quad,
                                                floatx4 acc[4][4]) {
  bf16x8 af[4], bfr[4];
#pragma unroll
  for (int i = 0; i < 4; ++i)
    af[i] = *reinterpret_cast<const bf16x8*>(&As[(wm + i * 16 + l15) * 32 + quad * 8]);
#pragma unroll
  for (int j = 0; j < 4; ++j)
    bfr[j] = *reinterpret_cast<const bf16x8*>(&Bs[(wn + j * 16 + l15) * 32 + quad * 8]);
#pragma unroll
  for (int i = 0; i < 4; ++i)
#pragma unroll
    for (int j = 0; j < 4; ++j)
      acc[i][j] = __builtin_amdgcn_mfma_f32_16x16x32_bf16(af[i], bfr[j], acc[i][j], 0, 0, 0);
}

// ---------------- K0: kv_cache fp32 -> bf16  +  q_rope * SCALE -> qc2 ----------------
// qc2 layout (A-fragment order): elem (t, h, c) at
// ((t*18 + (c>>5))*128 + h)*32 + (c&31). rope covers c in [512,576) -> ks 16,17.
__global__ void prep(const float* __restrict__ kv, unsigned short* __restrict__ kvb,
                     const float* __restrict__ q, unsigned short* __restrict__ qc2) {
  int b = blockIdx.x;
  if (b < 4608) {
    int i = b * 256 + threadIdx.x;  // per 4 elems, range sized exactly
    float4 v = reinterpret_cast<const float4*>(kv)[i];
    ushort4 o;
    o.x = f2bf(v.x); o.y = f2bf(v.y); o.z = f2bf(v.z); o.w = f2bf(v.w);
    reinterpret_cast<ushort4*>(kvb)[i] = o;
  } else {
    int i = (b - 4608) * 256 + threadIdx.x;  // 512*128*64 total
    int r = i & 63;
    int th = i >> 6;  // t*128 + h
    int t = th >> 7, h = th & 127;
    qc2[(((size_t)t * 18 + 16 + (r >> 5)) * 128 + h) * 32 + (r & 31)] =
        f2bf(q[(size_t)th * 192 + 128 + r] * SCALE);
  }
}

// ---------------- K1: q_lat = per-head (T x 128) @ (512 x 128)^T, * SCALE ----------------
// grid (128, 16): x = h (stride-128 siblings -> same XCD). Writes qc2 frag order.
__global__ __launch_bounds__(256) void qlat_gemm(const float* __restrict__ q,
                                                 const float* __restrict__ kb,
                                                 unsigned short* __restrict__ qc2) {
  const int h = blockIdx.x;
  const int tm = (blockIdx.y & 3) * 128;   // token tile
  const int tn = (blockIdx.y >> 2) * 128;  // lora-dim tile
  __shared__ __align__(16) unsigned short As[128 * 32];
  __shared__ __align__(16) unsigned short Bs[128 * 32];
  const int tid = threadIdx.x;
  const int lane = tid & 63, wave = tid >> 6;
  const int wm = (wave & 1) * 64, wn = (wave >> 1) * 64;
  const int l15 = lane & 15, quad = lane >> 4;
  const int r0 = tid >> 2, cg = tid & 3;  // chunk row, col-group(8)
  const float* a0 = q + ((size_t)(tm + r0) * 128 + h) * 192 + cg * 8;
  const float* a1 = q + ((size_t)(tm + r0 + 64) * 128 + h) * 192 + cg * 8;
  const float* b0 = kb + ((size_t)h * 512 + tn + r0) * 128 + cg * 8;
  const float* b1 = b0 + (size_t)64 * 128;
  floatx4 acc[4][4] = {};
  for (int ks = 0; ks < 4; ++ks) {  // contraction 128 = 4*32
    stage8_f32(a0 + ks * 32, &As[tid * 8]);
    stage8_f32(a1 + ks * 32, &As[2048 + tid * 8]);
    stage8_f32(b0 + ks * 32, &Bs[tid * 8]);
    stage8_f32(b1 + ks * 32, &Bs[2048 + tid * 8]);
    __syncthreads();
    mfma_4x4(As, Bs, wm, wn, l15, quad, acc);
    __syncthreads();
  }
#pragma unroll
  for (int i = 0; i < 4; ++i) {
    const int row = wm + i * 16 + quad * 4;  // token-local
#pragma unroll
    for (int j = 0; j < 4; ++j) {
      const int c = tn + wn + j * 16 + l15;  // lora-dim (global)
      const int ks2 = c >> 5, kk = c & 31;
#pragma unroll
      for (int r = 0; r < 4; ++r) {
        const int t = tm + row + r;
        qc2[(((size_t)t * 18 + ks2) * 128 + h) * 32 + kk] = f2bf(acc[i][j][r] * SCALE);
      }
    }
  }
}

// ---------------- K2: scores_fused = softmax_rows(Qc2 @ KVsel^T) -> P2 ----------------
// grid (512): one block per token, 512 threads / 8 waves (2 blk/CU, 16 w/CU).
// Wave = (wave>>2) head-half (64h) x (wave&3) key-quarter (128k); acc 4x8 ->
// each 1KB B-frag read by only 2 waves. Staging: Bs[2][512x32] (64KB, depth-2);
// DMA d=0..3: key=d*128+(tid>>2), c-sub=(tid&3)*8 -> lane-linear LDS ==
// row-major [512][32]. Gather indices loaded ONCE. vm-queue at iter top:
// [DMA(ks)x4, an(ks)x4] -> uniform vmcnt(4) retires DMA(ks) (fences pin order).
__global__ __launch_bounds__(512) void scores_fused(const unsigned short* __restrict__ qc2,
                                                    const unsigned short* __restrict__ kvb,
                                                    const int* __restrict__ topk,
                                                    unsigned short* __restrict__ P2) {
  const int t = blockIdx.x;
  __shared__ __align__(16) unsigned short Bs[2][512 * 32];  // 64KB
  __shared__ __align__(16) float redmx[128][4];             // 2KB
  __shared__ __align__(16) float redsm[128][4];             // 2KB
  const int tid = threadIdx.x;
  const int lane = tid & 63, wave = tid >> 6;  // 0..7
  const int wm2 = (wave >> 2) * 64;  // head half
  const int wkq = wave & 3;          // key quarter
  const int l15 = lane & 15, quad = lane >> 4;
  const int keyD = tid >> 2;         // 0..127
  const int cD = (tid & 3) * 8;
  const int* tkrow = topk + t * 512;
  const int gi0 = tkrow[0 * 128 + keyD];
  const int gi1 = tkrow[1 * 128 + keyD];
  const int gi2 = tkrow[2 * 128 + keyD];
  const int gi3 = tkrow[3 * 128 + keyD];
  const unsigned short* g0 = kvb + (size_t)gi0 * 576 + cD;
  const unsigned short* g1 = kvb + (size_t)gi1 * 576 + cD;
  const unsigned short* g2 = kvb + (size_t)gi2 * 576 + cD;
  const unsigned short* g3 = kvb + (size_t)gi3 * 576 + cD;
  // A-frag base in qc2: ((t*18+ks)*128 + wm2+i*16+l15)*32 + quad*8
  const unsigned short* aab =
      qc2 + ((size_t)t * 2304 + wm2 + l15) * 32 + quad * 8;
  floatx4 acc[4][8] = {};
  // prologue: DMA(0)x4 -> Bs[0] (oldest, pinned), then af(0) regs
  ldsdma16(g0, &Bs[0][0 * 4096 + tid * 8]);
  ldsdma16(g1, &Bs[0][1 * 4096 + tid * 8]);
  ldsdma16(g2, &Bs[0][2 * 4096 + tid * 8]);
  ldsdma16(g3, &Bs[0][3 * 4096 + tid * 8]);
  issue_fence();
  bf16x8 af[4], an[4];
#pragma unroll
  for (int i = 0; i < 4; ++i)
    af[i] = *reinterpret_cast<const bf16x8*>(aab + i * 512);
  for (int ks = 0; ks < 18; ++ks) {  // contraction 576 = 18*32
    asm volatile("s_waitcnt vmcnt(4)" ::: "memory");  // DMA(ks) landed (this wave)
    __builtin_amdgcn_s_barrier();                     // ... for ALL waves
    if (ks < 17) {
      const int nb = (ks + 1) & 1;
      ldsdma16(g0 + (ks + 1) * 32, &Bs[nb][0 * 4096 + tid * 8]);
      ldsdma16(g1 + (ks + 1) * 32, &Bs[nb][1 * 4096 + tid * 8]);
      ldsdma16(g2 + (ks + 1) * 32, &Bs[nb][2 * 4096 + tid * 8]);
      ldsdma16(g3 + (ks + 1) * 32, &Bs[nb][3 * 4096 + tid * 8]);
      issue_fence();  // DMA older than an loads: vm queue order == comments
#pragma unroll
      for (int i = 0; i < 4; ++i)
        an[i] = *reinterpret_cast<const bf16x8*>(
            aab + (size_t)(ks + 1) * 4096 + i * 512);
    }
    const unsigned short* bb = &Bs[ks & 1][0];
#pragma unroll
    for (int j = 0; j < 8; ++j) {
      const bf16x8 bfr = *reinterpret_cast<const bf16x8*>(
          &bb[(wkq * 128 + j * 16 + l15) * 32 + quad * 8]);
#pragma unroll
      for (int i = 0; i < 4; ++i)
        acc[i][j] = __builtin_amdgcn_mfma_f32_16x16x32_bf16(af[i], bfr, acc[i][j], 0, 0, 0);
    }
#pragma unroll
    for (int i = 0; i < 4; ++i) af[i] = an[i];
  }
  // ---- fused softmax epilogue ----
  // D layout: head = wm2 + i*16 + quad*4 + r ; key = wkq*128 + j*16 + l15
  float fm[4][4], inv[4][4];
#pragma unroll
  for (int i = 0; i < 4; ++i)
#pragma unroll
    for (int r = 0; r < 4; ++r) {
      float m = acc[i][0][r];
#pragma unroll
      for (int j = 1; j < 8; ++j) m = fmaxf(m, acc[i][j][r]);
#pragma unroll
      for (int off = 1; off <= 8; off <<= 1) m = fmaxf(m, __shfl_xor(m, off, 64));
      if (l15 == 0) redmx[wm2 + i * 16 + quad * 4 + r][wkq] = m;
    }
  __syncthreads();
#pragma unroll
  for (int i = 0; i < 4; ++i)
#pragma unroll
    for (int r = 0; r < 4; ++r) {
      const float4 q4 =
          *reinterpret_cast<const float4*>(redmx[wm2 + i * 16 + quad * 4 + r]);
      fm[i][r] = fmaxf(fmaxf(q4.x, q4.y), fmaxf(q4.z, q4.w));
    }
#pragma unroll
  for (int i = 0; i < 4; ++i)
#pragma unroll
    for (int r = 0; r < 4; ++r) {
      float s = 0.f;
#pragma unroll
      for (int j = 0; j < 8; ++j) {
        const float e = __expf(acc[i][j][r] - fm[i][r]);
        acc[i][j][r] = e;
        s += e;
      }
#pragma unroll
      for (int off = 1; off <= 8; off <<= 1) s += __shfl_xor(s, off, 64);
      if (l15 == 0) redsm[wm2 + i * 16 + quad * 4 + r][wkq] = s;
    }
  __syncthreads();
#pragma unroll
  for (int i = 0; i < 4; ++i)
#pragma unroll
    for (int r = 0; r < 4; ++r) {
      const float4 q4 =
          *reinterpret_cast<const float4*>(redsm[wm2 + i * 16 + quad * 4 + r]);
      inv[i][r] = 1.0f / (q4.x + q4.y + q4.z + q4.w);
    }
  // write P2 in attn's A-frag order: ((t*16 + key>>5)*128 + head)*32 + (key&31)
#pragma unroll
  for (int i = 0; i < 4; ++i)
#pragma unroll
    for (int j = 0; j < 8; ++j) {
      const int ks2 = wkq * 4 + (j >> 1);
      const int co = (j & 1) * 16 + l15;
#pragma unroll
      for (int r = 0; r < 4; ++r) {
        const int head = wm2 + i * 16 + quad * 4 + r;
        P2[(((size_t)t * 16 + ks2) * 128 + head) * 32 + co] =
            f2bf(acc[i][j][r] * inv[i][r]);
      }
    }
}

// ---------------- K4: attn_lat = P2 @ KVsel[:, :512], FULL 128h x 512c per block ----------------
// grid (512): one block per token, 512 threads / 8 waves (2 blk/CU).
// Wave = (wave>>2) head-half (64h) x (wave&3) c-quarter (128c); acc 4x8.
// St[2][32k x 512c] (64KB, depth-2) subtiled for tr_read; DMA d=0..3:
// key = d*8 + (tid>>8)*4 + ((tid>>1)&3), c = ((tid>>3)&31)*16 + (tid&1)*8.
// vm-queue at iter top: ks<15: [DMA x4, a x4, idx x4] -> vmcnt(8);
// ks=15: [DMA x4, a x4] -> vmcnt(4). idx prefetch = 1 tile ahead.
__global__ __launch_bounds__(512) void attn_gemm(const unsigned short* __restrict__ P2,
                                                 const unsigned short* __restrict__ kvb,
                                                 const int* __restrict__ topk,
                                                 unsigned short* __restrict__ alat2) {
  const int t = blockIdx.x;
  __shared__ __align__(16) unsigned short St[2][32 * 512];  // 64KB
  const int tid = threadIdx.x;
  const int lane = tid & 63, wave = tid >> 6;  // 0..7
  const int wm = (wave >> 2) * 64;   // head half
  const int wc = wave & 3;           // c-quarter
  const int l15 = lane & 15, quad = lane >> 4;
  const int keyBase = (tid >> 8) * 4 + ((tid >> 1) & 3);     // 0..7
  const int cA = ((tid >> 3) & 31) * 16 + (tid & 1) * 8;     // 0..504
  const int* tkrow = topk + t * 512;
  // A-fragment base: P2[((t*16+ks)*128 + wm+i*16+l15)*32 + quad*8]
  const unsigned short* a_base =
      P2 + ((size_t)t * 2048 + wm + l15) * 32 + quad * 8;
  // tr_read: subtile (kq=2*quad+h01, ct=wc*8+j) at byte (kq*32+ct)*128;
  // lane addr = quad*8192 + wc*1024 + l15*8; offsets j*128 (+4096 for h01=1)
  const unsigned int tra0 = lds_addr(&St[0][0]) + quad * 8192 + wc * 1024 + l15 * 8;
  floatx4 acc[4][8] = {};
  bf16x8 a_cur[4], a_nxt[4];
  int ip0, ip1, ip2, ip3;  // gather indices for tile ks+1
  {
#pragma unroll
    for (int d = 0; d < 4; ++d) {
      const int k0 = tkrow[d * 8 + keyBase];
      ldsdma16(kvb + (size_t)k0 * 576 + cA, &St[0][d * 4096 + tid * 8]);
    }
    issue_fence();  // DMA(0) = oldest 4 vm ops
#pragma unroll
    for (int i = 0; i < 4; ++i)
      a_cur[i] = *reinterpret_cast<const bf16x8*>(a_base + (size_t)i * 16 * 32);
    ip0 = tkrow[32 + 0 * 8 + keyBase];
    ip1 = tkrow[32 + 1 * 8 + keyBase];
    ip2 = tkrow[32 + 2 * 8 + keyBase];
    ip3 = tkrow[32 + 3 * 8 + keyBase];
  }
  for (int ks = 0; ks < 16; ++ks) {
    if (ks < 15) asm volatile("s_waitcnt vmcnt(8)" ::: "memory");  // DMA(ks) landed
    else         asm volatile("s_waitcnt vmcnt(4)" ::: "memory");
    __builtin_amdgcn_s_barrier();  // St[ks&1] full for all waves; other buf free
    const unsigned int tra = tra0 + (ks & 1) * 32768;
    if (ks < 15) {
      const int nb = (ks + 1) & 1;
      ldsdma16(kvb + (size_t)ip0 * 576 + cA, &St[nb][0 * 4096 + tid * 8]);
      ldsdma16(kvb + (size_t)ip1 * 576 + cA, &St[nb][1 * 4096 + tid * 8]);
      ldsdma16(kvb + (size_t)ip2 * 576 + cA, &St[nb][2 * 4096 + tid * 8]);
      ldsdma16(kvb + (size_t)ip3 * 576 + cA, &St[nb][3 * 4096 + tid * 8]);
      issue_fence();  // DMA oldest of this iter's vm ops
#pragma unroll
      for (int i = 0; i < 4; ++i)
        a_nxt[i] = *reinterpret_cast<const bf16x8*>(
            a_base + ((size_t)(ks + 1) * 128 + i * 16) * 32);
      if (ks < 14) {
        ip0 = tkrow[(ks + 2) * 32 + 0 * 8 + keyBase];
        ip1 = tkrow[(ks + 2) * 32 + 1 * 8 + keyBase];
        ip2 = tkrow[(ks + 2) * 32 + 2 * 8 + keyBase];
        ip3 = tkrow[(ks + 2) * 32 + 3 * 8 + keyBase];
      }
    }
    uint32x2 rl0, rl1, rl2, rl3, rl4, rl5, rl6, rl7;
    uint32x2 rh0, rh1, rh2, rh3, rh4, rh5, rh6, rh7;
    TR64(rl0, tra, "0");    TR64(rh0, tra, "4096");
    TR64(rl1, tra, "128");  TR64(rh1, tra, "4224");
    TR64(rl2, tra, "256");  TR64(rh2, tra, "4352");
    TR64(rl3, tra, "384");  TR64(rh3, tra, "4480");
    TR64(rl4, tra, "512");  TR64(rh4, tra, "4608");
    TR64(rl5, tra, "640");  TR64(rh5, tra, "4736");
    TR64(rl6, tra, "768");  TR64(rh6, tra, "4864");
    TR64(rl7, tra, "896");  TR64(rh7, tra, "4992");
    asm volatile("s_waitcnt lgkmcnt(0)");   // tr_reads complete
    __builtin_amdgcn_sched_barrier(0);      // rule #18: pin MFMAs after the wait
    bf16x8 bfr[8];
    {
      uint32x4 w;
      w.x = rl0.x; w.y = rl0.y; w.z = rh0.x; w.w = rh0.y; bfr[0] = __builtin_bit_cast(bf16x8, w);
      w.x = rl1.x; w.y = rl1.y; w.z = rh1.x; w.w = rh1.y; bfr[1] = __builtin_bit_cast(bf16x8, w);
      w.x = rl2.x; w.y = rl2.y; w.z = rh2.x; w.w = rh2.y; bfr[2] = __builtin_bit_cast(bf16x8, w);
      w.x = rl3.x; w.y = rl3.y; w.z = rh3.x; w.w = rh3.y; bfr[3] = __builtin_bit_cast(bf16x8, w);
      w.x = rl4.x; w.y = rl4.y; w.z = rh4.x; w.w = rh4.y; bfr[4] = __builtin_bit_cast(bf16x8, w);
      w.x = rl5.x; w.y = rl5.y; w.z = rh5.x; w.w = rh5.y; bfr[5] = __builtin_bit_cast(bf16x8, w);
      w.x = rl6.x; w.y = rl6.y; w.z = rh6.x; w.w = rh6.y; bfr[6] = __builtin_bit_cast(bf16x8, w);
      w.x = rl7.x; w.y = rl7.y; w.z = rh7.x; w.w = rh7.y; bfr[7] = __builtin_bit_cast(bf16x8, w);
    }
#pragma unroll
    for (int i = 0; i < 4; ++i)
#pragma unroll
      for (int j = 0; j < 8; ++j)
        acc[i][j] =
            __builtin_amdgcn_mfma_f32_16x16x32_bf16(a_cur[i], bfr[j], acc[i][j], 0, 0, 0);
#pragma unroll
    for (int i = 0; i < 4; ++i) a_cur[i] = a_nxt[i];
  }
  // write alat2 in out_gemm's A-fragment order:
  // elem (h=row+r, t, c) at ((h*16 + (c>>5))*512 + t)*32 + (c&31)
#pragma unroll
  for (int i = 0; i < 4; ++i) {
    const int row = wm + i * 16 + quad * 4;  // head
#pragma unroll
    for (int j = 0; j < 8; ++j) {
      const int c = wc * 128 + j * 16 + l15;  // c
      const int ks2 = c >> 5, kk = c & 31;
#pragma unroll
      for (int r = 0; r < 4; ++r)
        alat2[(((size_t)(row + r) * 16 + ks2) * 512 + t) * 32 + kk] =
            f2bf(acc[i][j][r]);
    }
  }
}

// ---------------- K5: out (128t x 128v tile) = attn_lat[h] @ v_b[h]^T ----------------
// grid (128, 4): x = h (stride-128 siblings -> same XCD). A-frags DIRECT from
// alat2 (fragment order -> coalesced); only B (fp32 vb) staged. __syncthreads.
__global__ __launch_bounds__(256) void out_gemm(const unsigned short* __restrict__ alat2,
                                                const float* __restrict__ vb,
                                                float* __restrict__ out) {
  const int h = blockIdx.x;
  const int tm = blockIdx.y * 128;  // token tile
  __shared__ __align__(16) unsigned short Bs[128 * 32];
  const int tid = threadIdx.x;
  const int lane = tid & 63, wave = tid >> 6;
  const int wm = (wave & 1) * 64, wn = (wave >> 1) * 64;
  const int l15 = lane & 15, quad = lane >> 4;
  const int r0 = tid >> 2, cg = tid & 3;
  const unsigned short* aab =
      alat2 + ((size_t)h * 8192 + tm + wm + l15) * 32 + quad * 8;
  const float* b0 = vb + ((size_t)h * 128 + r0) * 512 + cg * 8;
  const float* b1 = b0 + (size_t)64 * 512;
  floatx4 acc[4][4] = {};
  for (int ks = 0; ks < 16; ++ks) {  // contraction 512 = 16*32
    stage8_f32(b0 + ks * 32, &Bs[tid * 8]);
    stage8_f32(b1 + ks * 32, &Bs[2048 + tid * 8]);
    __syncthreads();
    bf16x8 af[4], bfr[4];
#pragma unroll
    for (int i = 0; i < 4; ++i)
      af[i] = *reinterpret_cast<const bf16x8*>(
          aab + (size_t)ks * 16384 + i * 512);
#pragma unroll
    for (int j = 0; j < 4; ++j)
      bfr[j] = *reinterpret_cast<const bf16x8*>(
          &Bs[(wn + j * 16 + l15) * 32 + quad * 8]);
#pragma unroll
    for (int i = 0; i < 4; ++i)
#pragma unroll
      for (int j = 0; j < 4; ++j)
        acc[i][j] =
            __builtin_amdgcn_mfma_f32_16x16x32_bf16(af[i], bfr[j], acc[i][j], 0, 0, 0);
    __syncthreads();
  }
#pragma unroll
  for (int i = 0; i < 4; ++i) {
    const int row = wm + i * 16 + quad * 4;  // token-local
#pragma unroll
    for (int j = 0; j < 4; ++j) {
      const int col = wn + j * 16 + l15;  // v
#pragma unroll
      for (int r = 0; r < 4; ++r) {
        const int t = tm + row + r;
        out[((size_t)t * 128 + h) * 128 + col] = acc[i][j][r];
      }
    }
  }
}

extern "C" void kernel_launch(void* const* d_in, const int* in_sizes, int n_in,
                              void* d_out, int out_size, void* d_ws, size_t ws_size,
                              hipStream_t stream) {
  const float* q = (const float*)d_in[0];         // (512,128,192)
  const float* kv = (const float*)d_in[1];        // (8192,576)
  const int* topk = (const int*)d_in[2];          // (512,512)
  const float* kb = (const float*)d_in[3];        // (128,512,128)
  const float* vb = (const float*)d_in[4];        // (128,128,512)
  float* out = (float*)d_out;                     // (512,128,128)

  char* ws = (char*)d_ws;
  unsigned short* kvb = (unsigned short*)ws;                        // 9,437,184 B
  unsigned short* qc2 = (unsigned short*)(ws + 9437184);            // 75,497,472 B
  unsigned short* P2 = (unsigned short*)(ws + 9437184 + 75497472);  // 67,108,864 B
  // P2 must NOT alias qc2 (scores_fused reads qc2 while writing P2).
  // alat2 reuses qc2 (dead after scores_fused). Total ws unchanged: 152 MB.
  unsigned short* alat2 = qc2;

  prep<<<dim3(20992), dim3(256), 0, stream>>>(kv, kvb, q, qc2);
  qlat_gemm<<<dim3(128, 16), dim3(256), 0, stream>>>(q, kb, qc2);
  scores_fused<<<dim3(512), dim3(512), 0, stream>>>(qc2, kvb, topk, P2);
  attn_gemm<<<dim3(512), dim3(512), 0, stream>>>(P2, kvb, topk, alat2);
  out_gemm<<<dim3(128, 4), dim3(256), 0, stream>>>(alat2, vb, out);
}